// Round 1
// baseline (305.899 us; speedup 1.0000x reference)
//
#include <hip/hip_runtime.h>

typedef unsigned short u16;
typedef unsigned int u32;
typedef __attribute__((ext_vector_type(8))) short short8;
typedef __attribute__((ext_vector_type(4))) float f32x4;

#define T_TOK 4096
#define DIM   1024
#define NEXP  16
#define INTER 512
#define NSH   1024
#define CAP   4096
#define BM 128
#define BN 128
#define BK 64

__device__ __forceinline__ u16 f2bf(float f) {
  union { float f; u32 u; } c; c.f = f;
  u32 u = c.u;
  return (u16)((u + 0x7FFFu + ((u >> 16) & 1u)) >> 16);
}

typedef __attribute__((address_space(1))) u32 u32_g;
typedef __attribute__((address_space(3))) u32 u32_l;
__device__ __forceinline__ void gload16(const u16* g, u16* l) {
  __builtin_amdgcn_global_load_lds((u32_g*)g, (u32_l*)l, 16, 0, 0);
}

// ---------------- gate: fp64 scores + group-limited top-2 routing ----------------
__global__ void __launch_bounds__(64) k_gate(const float* __restrict__ x,
                                             const float* __restrict__ gw,
                                             const float* __restrict__ gb,
                                             int* __restrict__ counts,
                                             int* __restrict__ bucket,
                                             float* __restrict__ tokw) {
  const int t = blockIdx.x;
  const int lane = threadIdx.x;
  const float* xr = x + (size_t)t * DIM;
  float xl[16];
#pragma unroll
  for (int i = 0; i < 16; ++i) xl[i] = xr[lane + 64 * i];
  double s[NEXP];
  for (int e = 0; e < NEXP; ++e) {
    const float* wr = gw + e * DIM;
    double p = 0.0;
#pragma unroll
    for (int i = 0; i < 16; ++i) p += (double)xl[i] * (double)wr[lane + 64 * i];
#pragma unroll
    for (int off = 32; off > 0; off >>= 1) p += __shfl_xor(p, off, 64);
    s[e] = p;
  }
  if (lane != 0) return;
  double m = s[0];
  for (int e = 1; e < NEXP; ++e) m = s[e] > m ? s[e] : m;
  double ex[NEXP], sum = 0.0;
  for (int e = 0; e < NEXP; ++e) { ex[e] = exp(s[e] - m); sum += ex[e]; }
  double orig[NEXP], sc[NEXP];
  for (int e = 0; e < NEXP; ++e) { orig[e] = ex[e] / sum; sc[e] = orig[e] + (double)gb[e]; }
  // group scores = sum of top-2 within each group of 4
  double gs[4];
  for (int g = 0; g < 4; ++g) {
    double m1 = -1e300, m2 = -1e300;
    for (int j = 0; j < 4; ++j) {
      double v = sc[g * 4 + j];
      if (v > m1) { m2 = m1; m1 = v; } else if (v > m2) m2 = v;
    }
    gs[g] = m1 + m2;
  }
  int g1 = 0;
  for (int g = 1; g < 4; ++g) if (gs[g] > gs[g1]) g1 = g;       // first-max tie-break
  int g2 = -1;
  for (int g = 0; g < 4; ++g) { if (g == g1) continue; if (g2 < 0 || gs[g] > gs[g2]) g2 = g; }
  int e1 = -1, e2 = -1;
  for (int e = 0; e < NEXP; ++e) {
    int g = e >> 2;
    if (g != g1 && g != g2) continue;
    if (e1 < 0 || sc[e] > sc[e1]) e1 = e;
  }
  for (int e = 0; e < NEXP; ++e) {
    int g = e >> 2;
    if ((g != g1 && g != g2) || e == e1) continue;
    if (e2 < 0 || sc[e] > sc[e2]) e2 = e;
  }
  tokw[2 * t]     = (float)orig[e1];   // ROUTE_SCALE = 1.0
  tokw[2 * t + 1] = (float)orig[e2];
  int p0 = atomicAdd(&counts[e1], 1); bucket[e1 * CAP + p0] = 2 * t;
  int p1 = atomicAdd(&counts[e2], 1); bucket[e2 * CAP + p1] = 2 * t + 1;
}

// ---------------- fp32 -> bf16 convert (vectorized) ----------------
__global__ void k_cvt(const float* __restrict__ src, u16* __restrict__ dst, int n) {
  int i = (blockIdx.x * blockDim.x + threadIdx.x) * 4;
  if (i >= n) return;
  float4 v = *reinterpret_cast<const float4*>(src + i);
  ushort4 o;
  o.x = f2bf(v.x); o.y = f2bf(v.y); o.z = f2bf(v.z); o.w = f2bf(v.w);
  *reinterpret_cast<ushort4*>(dst + i) = o;
}

// ---------------- transpose-convert: src [b][R][C] f32 -> dst [b][C][R] bf16 ----------------
__global__ void k_tr(const float* __restrict__ src, u16* __restrict__ dst, int R, int C) {
  __shared__ float tile[32][33];
  const size_t boff = (size_t)blockIdx.z * R * C;
  src += boff; dst += boff;
  int c0 = blockIdx.x * 32, r0 = blockIdx.y * 32;
  int tx = threadIdx.x, ty = threadIdx.y;
#pragma unroll
  for (int i = 0; i < 4; ++i)
    tile[ty + 8 * i][tx] = src[(size_t)(r0 + ty + 8 * i) * C + c0 + tx];
  __syncthreads();
#pragma unroll
  for (int i = 0; i < 4; ++i)
    dst[(size_t)(c0 + ty + 8 * i) * R + r0 + tx] = f2bf(tile[tx][ty + 8 * i]);
}

// ---------------- GEMM1: h = silu(A@B1^T + b1) * (A@B3^T + b3), bf16 out ----------------
// A: [*, K] bf16 (gathered rows if GATHER); B1/B3: [E][N][K] bf16 (pre-transposed)
template <bool GATHER>
__global__ void __launch_bounds__(256, 2) k_gemm1(
    const u16* __restrict__ A, const u16* __restrict__ B1, const u16* __restrict__ B3,
    const float* __restrict__ bias1, const float* __restrict__ bias3,
    u16* __restrict__ H, const int* __restrict__ counts, const int* __restrict__ bucket,
    int N, int K) {
  const int e = blockIdx.z;
  const int M = GATHER ? counts[e] : T_TOK;
  const int mt = blockIdx.y;
  if (mt * BM >= M) return;
  const int nt = blockIdx.x;
  const int tid = threadIdx.x;
  const int lane = tid & 63;
  const int wid = tid >> 6;

  __shared__ __align__(16) u16 lA[BM * BK];
  __shared__ __align__(16) u16 lB1[BM * BK];
  __shared__ __align__(16) u16 lB3[BM * BK];

  const int srow = tid >> 3;                  // 0..31 staging row
  const int sc16 = tid & 7;                   // 16B column
  const int scsw = (sc16 ^ (srow & 7)) * 8;   // inverse-swizzled source column (elements)
  const int* bkt = bucket + e * CAP;

  const u16* aptr[4]; const u16* b1ptr[4]; const u16* b3ptr[4];
#pragma unroll
  for (int p = 0; p < 4; ++p) {
    int r = mt * BM + srow + p * 32;
    size_t arow;
    if (GATHER) { int pos = r < M ? r : M - 1; arow = (size_t)(bkt[pos] >> 1); }
    else arow = (size_t)r;
    aptr[p] = A + arow * K + scsw;
    size_t nrow = (size_t)e * N + nt * BN + srow + p * 32;
    b1ptr[p] = B1 + nrow * K + scsw;
    b3ptr[p] = B3 + nrow * K + scsw;
  }

  f32x4 acc1[4][4], acc3[4][4];
#pragma unroll
  for (int i = 0; i < 4; ++i)
#pragma unroll
    for (int j = 0; j < 4; ++j) {
      acc1[i][j] = f32x4{0.f, 0.f, 0.f, 0.f};
      acc3[i][j] = f32x4{0.f, 0.f, 0.f, 0.f};
    }

  const int wm = wid >> 1, wn = wid & 1;
  const int fr = lane & 15, fs = lane >> 4;
  const int csA = fr & 7;

  for (int kt = 0; kt < K; kt += BK) {
#pragma unroll
    for (int p = 0; p < 4; ++p) {
      int ldso = (srow + 32 * p) * BK + sc16 * 8;   // linear dest (= tid*8 + p*2048)
      gload16(aptr[p] + kt, &lA[ldso]);
      gload16(b1ptr[p] + kt, &lB1[ldso]);
      gload16(b3ptr[p] + kt, &lB3[ldso]);
    }
    __syncthreads();
#pragma unroll
    for (int kk = 0; kk < 2; ++kk) {
      const int c = ((kk * 4 + fs) ^ csA) * 8;      // swizzled fragment column
      short8 af[4];
#pragma unroll
      for (int mi = 0; mi < 4; ++mi)
        af[mi] = *reinterpret_cast<const short8*>(&lA[(wm * 64 + mi * 16 + fr) * BK + c]);
#pragma unroll
      for (int ni = 0; ni < 4; ++ni) {
        short8 b1f = *reinterpret_cast<const short8*>(&lB1[(wn * 64 + ni * 16 + fr) * BK + c]);
        short8 b3f = *reinterpret_cast<const short8*>(&lB3[(wn * 64 + ni * 16 + fr) * BK + c]);
#pragma unroll
        for (int mi = 0; mi < 4; ++mi) {
          acc1[mi][ni] = __builtin_amdgcn_mfma_f32_16x16x32_bf16(af[mi], b1f, acc1[mi][ni], 0, 0, 0);
          acc3[mi][ni] = __builtin_amdgcn_mfma_f32_16x16x32_bf16(af[mi], b3f, acc3[mi][ni], 0, 0, 0);
        }
      }
    }
    __syncthreads();
  }

  const float* bp1 = bias1 + (size_t)e * N;
  const float* bp3 = bias3 + (size_t)e * N;
#pragma unroll
  for (int mi = 0; mi < 4; ++mi) {
#pragma unroll
    for (int j = 0; j < 4; ++j) {
      int p = mt * BM + wm * 64 + mi * 16 + fs * 4 + j;   // C/D: row=(lane>>4)*4+j
      if (p >= M) continue;
      size_t hrow = GATHER ? (size_t)bkt[p] : (size_t)p;
      u16* hp = H + hrow * N;
#pragma unroll
      for (int ni = 0; ni < 4; ++ni) {
        int gcol = nt * BN + wn * 64 + ni * 16 + fr;      // C/D: col=lane&15
        float v1 = acc1[mi][ni][j] + bp1[gcol];
        float v3 = acc3[mi][ni][j] + bp3[gcol];
        float hv = (v1 / (1.0f + __expf(-v1))) * v3;
        hp[gcol] = f2bf(hv);
      }
    }
  }
}

// ---------------- GEMM2: out = (A@B^T + bias) [*w, scatter-atomic | plain store] ----------------
template <bool GATHER>
__global__ void __launch_bounds__(256, 2) k_gemm2(
    const u16* __restrict__ A, const u16* __restrict__ B,
    const float* __restrict__ bias, const float* __restrict__ tokw,
    float* __restrict__ OUT, const int* __restrict__ counts, const int* __restrict__ bucket,
    int N, int K) {
  const int e = blockIdx.z;
  const int M = GATHER ? counts[e] : T_TOK;
  const int mt = blockIdx.y;
  if (mt * BM >= M) return;
  const int nt = blockIdx.x;
  const int tid = threadIdx.x;
  const int lane = tid & 63;
  const int wid = tid >> 6;

  __shared__ __align__(16) u16 lA[BM * BK];
  __shared__ __align__(16) u16 lB[BM * BK];

  const int srow = tid >> 3;
  const int sc16 = tid & 7;
  const int scsw = (sc16 ^ (srow & 7)) * 8;
  const int* bkt = bucket + e * CAP;

  const u16* aptr[4]; const u16* bptr[4];
#pragma unroll
  for (int p = 0; p < 4; ++p) {
    int r = mt * BM + srow + p * 32;
    size_t arow;
    if (GATHER) { int pos = r < M ? r : M - 1; arow = (size_t)bkt[pos]; }
    else arow = (size_t)r;
    aptr[p] = A + arow * K + scsw;
    size_t nrow = (size_t)e * N + nt * BN + srow + p * 32;
    bptr[p] = B + nrow * K + scsw;
  }

  f32x4 acc[4][4];
#pragma unroll
  for (int i = 0; i < 4; ++i)
#pragma unroll
    for (int j = 0; j < 4; ++j) acc[i][j] = f32x4{0.f, 0.f, 0.f, 0.f};

  const int wm = wid >> 1, wn = wid & 1;
  const int fr = lane & 15, fs = lane >> 4;
  const int csA = fr & 7;

  for (int kt = 0; kt < K; kt += BK) {
#pragma unroll
    for (int p = 0; p < 4; ++p) {
      int ldso = (srow + 32 * p) * BK + sc16 * 8;
      gload16(aptr[p] + kt, &lA[ldso]);
      gload16(bptr[p] + kt, &lB[ldso]);
    }
    __syncthreads();
#pragma unroll
    for (int kk = 0; kk < 2; ++kk) {
      const int c = ((kk * 4 + fs) ^ csA) * 8;
      short8 af[4];
#pragma unroll
      for (int mi = 0; mi < 4; ++mi)
        af[mi] = *reinterpret_cast<const short8*>(&lA[(wm * 64 + mi * 16 + fr) * BK + c]);
#pragma unroll
      for (int ni = 0; ni < 4; ++ni) {
        short8 bf = *reinterpret_cast<const short8*>(&lB[(wn * 64 + ni * 16 + fr) * BK + c]);
#pragma unroll
        for (int mi = 0; mi < 4; ++mi)
          acc[mi][ni] = __builtin_amdgcn_mfma_f32_16x16x32_bf16(af[mi], bf, acc[mi][ni], 0, 0, 0);
      }
    }
    __syncthreads();
  }

#pragma unroll
  for (int mi = 0; mi < 4; ++mi) {
#pragma unroll
    for (int j = 0; j < 4; ++j) {
      int p = mt * BM + wm * 64 + mi * 16 + fs * 4 + j;
      if (p >= M) continue;
#pragma unroll
      for (int ni = 0; ni < 4; ++ni) {
        int gcol = nt * BN + wn * 64 + ni * 16 + fr;
        float v = acc[mi][ni][j] + bias[(size_t)e * N + gcol];
        if (GATHER) {
          int slot = bkt[p];
          float w = tokw[slot];
          atomicAdd(&OUT[(size_t)(slot >> 1) * DIM + gcol], v * w);
        } else {
          OUT[(size_t)p * DIM + gcol] = v;
        }
      }
    }
  }
}

extern "C" void kernel_launch(void* const* d_in, const int* in_sizes, int n_in,
                              void* d_out, int out_size, void* d_ws, size_t ws_size,
                              hipStream_t stream) {
  const float* x   = (const float*)d_in[0];
  const float* gw  = (const float*)d_in[1];
  const float* gb  = (const float*)d_in[2];
  const float* We1 = (const float*)d_in[3];
  const float* be1 = (const float*)d_in[4];
  const float* We2 = (const float*)d_in[5];
  const float* be2 = (const float*)d_in[6];
  const float* We3 = (const float*)d_in[7];
  const float* be3 = (const float*)d_in[8];
  const float* ws1 = (const float*)d_in[9];
  const float* bs1 = (const float*)d_in[10];
  const float* ws2 = (const float*)d_in[11];
  const float* bs2 = (const float*)d_in[12];
  const float* ws3 = (const float*)d_in[13];
  const float* bs3 = (const float*)d_in[14];
  float* out = (float*)d_out;

  // workspace carve (all regions 256B aligned); total ~70.3 MB
  char* w = (char*)d_ws;
  int*   counts = (int*)w;   w += 256;
  int*   bucket = (int*)w;   w += (size_t)NEXP * CAP * 4;
  float* tokw   = (float*)w; w += (size_t)2 * T_TOK * 4;
  u16*   xb     = (u16*)w;   w += (size_t)T_TOK * DIM * 2;
  u16*   w1t    = (u16*)w;   w += (size_t)NEXP * INTER * DIM * 2;
  u16*   w3t    = (u16*)w;   w += (size_t)NEXP * INTER * DIM * 2;
  u16*   w2t    = (u16*)w;   w += (size_t)NEXP * DIM * INTER * 2;
  u16*   s1t    = (u16*)w;   w += (size_t)NSH * DIM * 2;
  u16*   s3t    = (u16*)w;   w += (size_t)NSH * DIM * 2;
  u16*   s2t    = (u16*)w;   w += (size_t)DIM * NSH * 2;
  u16*   hbuf   = (u16*)w;   w += (size_t)2 * T_TOK * INTER * 2;  // aliased: hs [T][NSH] then h [2T][INTER]

  hipMemsetAsync(counts, 0, 64, stream);
  k_cvt<<<(T_TOK * DIM) / (256 * 4), 256, 0, stream>>>(x, xb, T_TOK * DIM);
  dim3 tb(32, 8);
  k_tr<<<dim3(INTER / 32, DIM / 32, NEXP), tb, 0, stream>>>(We1, w1t, DIM, INTER);
  k_tr<<<dim3(INTER / 32, DIM / 32, NEXP), tb, 0, stream>>>(We3, w3t, DIM, INTER);
  k_tr<<<dim3(DIM / 32, INTER / 32, NEXP), tb, 0, stream>>>(We2, w2t, INTER, DIM);
  k_tr<<<dim3(NSH / 32, DIM / 32, 1), tb, 0, stream>>>(ws1, s1t, DIM, NSH);
  k_tr<<<dim3(NSH / 32, DIM / 32, 1), tb, 0, stream>>>(ws3, s3t, DIM, NSH);
  k_tr<<<dim3(DIM / 32, NSH / 32, 1), tb, 0, stream>>>(ws2, s2t, NSH, DIM);
  k_gate<<<T_TOK, 64, 0, stream>>>(x, gw, gb, counts, bucket, tokw);

  // shared expert path: writes z to every d_out element (plain stores)
  k_gemm1<false><<<dim3(NSH / BN, T_TOK / BM, 1), 256, 0, stream>>>(
      xb, s1t, s3t, bs1, bs3, hbuf, counts, bucket, NSH, DIM);
  k_gemm2<false><<<dim3(DIM / BN, T_TOK / BM, 1), 256, 0, stream>>>(
      hbuf, s2t, bs2, tokw, out, counts, bucket, DIM, NSH);
  // routed expert path: atomicAdd on top of z
  k_gemm1<true><<<dim3(INTER / BN, CAP / BM, NEXP), 256, 0, stream>>>(
      xb, w1t, w3t, be1, be3, hbuf, counts, bucket, INTER, DIM);
  k_gemm2<true><<<dim3(DIM / BN, CAP / BM, NEXP), 256, 0, stream>>>(
      hbuf, w2t, be2, tokw, out, counts, bucket, DIM, INTER);
}

// Round 2
// 255.724 us; speedup vs baseline: 1.1962x; 1.1962x over previous
//
#include <hip/hip_runtime.h>

typedef unsigned short u16;
typedef unsigned int u32;
typedef __attribute__((ext_vector_type(8))) short short8;
typedef __attribute__((ext_vector_type(4))) float f32x4;

#define T_TOK 4096
#define DIM   1024
#define NEXP  16
#define INTER 512
#define NSH   1024
#define CAP   4096
#define BM 128
#define BN 128
#define BK 64

__device__ __forceinline__ u16 f2bf(float f) {
  union { float f; u32 u; } c; c.f = f;
  u32 u = c.u;
  return (u16)((u + 0x7FFFu + ((u >> 16) & 1u)) >> 16);
}

typedef __attribute__((address_space(1))) u32 u32_g;
typedef __attribute__((address_space(3))) u32 u32_l;
__device__ __forceinline__ void gload16(const u16* g, u16* l) {
  __builtin_amdgcn_global_load_lds((u32_g*)g, (u32_l*)l, 16, 0, 0);
}

// ---------------- gate phase A: fp64 scores = x @ gw^T ----------------
// one thread per (token, expert, D-half); 16 tokens/block, 512 threads
__global__ void __launch_bounds__(512) k_score(const float* __restrict__ x,
                                               const float* __restrict__ gw,
                                               double* __restrict__ scores) {
  const int tid = threadIdx.x;
  const int h  = tid >> 8;          // 0..1 : half of D
  const int tk = (tid >> 4) & 15;   // 0..15: token within block
  const int e  = tid & 15;          // 0..15: expert
  const int t  = blockIdx.x * 16 + tk;
  const float* xr = x + (size_t)t * DIM + h * 512;
  const float* wr = gw + (size_t)e * DIM + h * 512;
  double p = 0.0;
#pragma unroll 8
  for (int i = 0; i < 128; ++i) {
    float4 xv = *reinterpret_cast<const float4*>(xr + i * 4);
    float4 wv = *reinterpret_cast<const float4*>(wr + i * 4);
    p += (double)xv.x * (double)wv.x;
    p += (double)xv.y * (double)wv.y;
    p += (double)xv.z * (double)wv.z;
    p += (double)xv.w * (double)wv.w;
  }
  __shared__ double part[512];
  part[tid] = p;
  __syncthreads();
  if (tid < 256) scores[(size_t)t * NEXP + e] = part[tid] + part[tid + 256];
}

// ---------------- gate phase B: softmax + group-limited top-2, one THREAD per token ----------------
__global__ void __launch_bounds__(256) k_route(const double* __restrict__ scores,
                                               const float* __restrict__ gb,
                                               int* __restrict__ counts,
                                               int* __restrict__ bucket,
                                               float* __restrict__ tokw) {
  const int t = blockIdx.x * 256 + threadIdx.x;
  double s[NEXP];
#pragma unroll
  for (int e = 0; e < NEXP; ++e) s[e] = scores[(size_t)t * NEXP + e];
  double m = s[0];
#pragma unroll
  for (int e = 1; e < NEXP; ++e) m = s[e] > m ? s[e] : m;
  double ex[NEXP], sum = 0.0;
#pragma unroll
  for (int e = 0; e < NEXP; ++e) { ex[e] = exp(s[e] - m); sum += ex[e]; }
  double orig[NEXP], sc[NEXP];
#pragma unroll
  for (int e = 0; e < NEXP; ++e) { orig[e] = ex[e] / sum; sc[e] = orig[e] + (double)gb[e]; }
  // group scores = sum of top-2 within each group of 4
  double gs[4];
#pragma unroll
  for (int g = 0; g < 4; ++g) {
    double m1 = -1e300, m2 = -1e300;
#pragma unroll
    for (int j = 0; j < 4; ++j) {
      double v = sc[g * 4 + j];
      if (v > m1) { m2 = m1; m1 = v; } else if (v > m2) m2 = v;
    }
    gs[g] = m1 + m2;
  }
  int g1 = 0;
  for (int g = 1; g < 4; ++g) if (gs[g] > gs[g1]) g1 = g;       // first-max tie-break (jax top_k)
  int g2 = -1;
  for (int g = 0; g < 4; ++g) { if (g == g1) continue; if (g2 < 0 || gs[g] > gs[g2]) g2 = g; }
  int e1 = -1, e2 = -1;
  for (int e = 0; e < NEXP; ++e) {
    int g = e >> 2;
    if (g != g1 && g != g2) continue;
    if (e1 < 0 || sc[e] > sc[e1]) e1 = e;
  }
  for (int e = 0; e < NEXP; ++e) {
    int g = e >> 2;
    if ((g != g1 && g != g2) || e == e1) continue;
    if (e2 < 0 || sc[e] > sc[e2]) e2 = e;
  }
  tokw[2 * t]     = (float)orig[e1];   // ROUTE_SCALE = 1.0
  tokw[2 * t + 1] = (float)orig[e2];
  int p0 = atomicAdd(&counts[e1], 1); bucket[e1 * CAP + p0] = 2 * t;
  int p1 = atomicAdd(&counts[e2], 1); bucket[e2 * CAP + p1] = 2 * t + 1;
}

// ---------------- fp32 -> bf16 convert (vectorized) ----------------
__global__ void k_cvt(const float* __restrict__ src, u16* __restrict__ dst, int n) {
  int i = (blockIdx.x * blockDim.x + threadIdx.x) * 4;
  if (i >= n) return;
  float4 v = *reinterpret_cast<const float4*>(src + i);
  ushort4 o;
  o.x = f2bf(v.x); o.y = f2bf(v.y); o.z = f2bf(v.z); o.w = f2bf(v.w);
  *reinterpret_cast<ushort4*>(dst + i) = o;
}

// ---------------- transpose-convert: src [b][R][C] f32 -> dst [b][C][R] bf16 ----------------
__global__ void k_tr(const float* __restrict__ src, u16* __restrict__ dst, int R, int C) {
  __shared__ float tile[32][33];
  const size_t boff = (size_t)blockIdx.z * R * C;
  src += boff; dst += boff;
  int c0 = blockIdx.x * 32, r0 = blockIdx.y * 32;
  int tx = threadIdx.x, ty = threadIdx.y;
#pragma unroll
  for (int i = 0; i < 4; ++i)
    tile[ty + 8 * i][tx] = src[(size_t)(r0 + ty + 8 * i) * C + c0 + tx];
  __syncthreads();
#pragma unroll
  for (int i = 0; i < 4; ++i)
    dst[(size_t)(c0 + ty + 8 * i) * R + r0 + tx] = f2bf(tile[tx][ty + 8 * i]);
}

// ---------------- GEMM1: h = silu(A@B1^T + b1) * (A@B3^T + b3), bf16 out ----------------
// A: [*, K] bf16 (gathered rows if GATHER); B1/B3: [E][N][K] bf16 (pre-transposed)
template <bool GATHER>
__global__ void __launch_bounds__(256, 2) k_gemm1(
    const u16* __restrict__ A, const u16* __restrict__ B1, const u16* __restrict__ B3,
    const float* __restrict__ bias1, const float* __restrict__ bias3,
    u16* __restrict__ H, const int* __restrict__ counts, const int* __restrict__ bucket,
    int N, int K) {
  const int e = blockIdx.z;
  const int M = GATHER ? counts[e] : T_TOK;
  const int mt = blockIdx.y;
  if (mt * BM >= M) return;
  const int nt = blockIdx.x;
  const int tid = threadIdx.x;
  const int lane = tid & 63;
  const int wid = tid >> 6;

  __shared__ __align__(16) u16 lA[BM * BK];
  __shared__ __align__(16) u16 lB1[BM * BK];
  __shared__ __align__(16) u16 lB3[BM * BK];

  const int srow = tid >> 3;                  // 0..31 staging row
  const int sc16 = tid & 7;                   // 16B column
  const int scsw = (sc16 ^ (srow & 7)) * 8;   // inverse-swizzled source column (elements)
  const int* bkt = bucket + e * CAP;

  const u16* aptr[4]; const u16* b1ptr[4]; const u16* b3ptr[4];
#pragma unroll
  for (int p = 0; p < 4; ++p) {
    int r = mt * BM + srow + p * 32;
    size_t arow;
    if (GATHER) { int pos = r < M ? r : M - 1; arow = (size_t)(bkt[pos] >> 1); }
    else arow = (size_t)r;
    aptr[p] = A + arow * K + scsw;
    size_t nrow = (size_t)e * N + nt * BN + srow + p * 32;
    b1ptr[p] = B1 + nrow * K + scsw;
    b3ptr[p] = B3 + nrow * K + scsw;
  }

  f32x4 acc1[4][4], acc3[4][4];
#pragma unroll
  for (int i = 0; i < 4; ++i)
#pragma unroll
    for (int j = 0; j < 4; ++j) {
      acc1[i][j] = f32x4{0.f, 0.f, 0.f, 0.f};
      acc3[i][j] = f32x4{0.f, 0.f, 0.f, 0.f};
    }

  const int wm = wid >> 1, wn = wid & 1;
  const int fr = lane & 15, fs = lane >> 4;
  const int csA = fr & 7;

  for (int kt = 0; kt < K; kt += BK) {
#pragma unroll
    for (int p = 0; p < 4; ++p) {
      int ldso = (srow + 32 * p) * BK + sc16 * 8;   // linear dest (= tid*8 + p*2048)
      gload16(aptr[p] + kt, &lA[ldso]);
      gload16(b1ptr[p] + kt, &lB1[ldso]);
      gload16(b3ptr[p] + kt, &lB3[ldso]);
    }
    __syncthreads();
#pragma unroll
    for (int kk = 0; kk < 2; ++kk) {
      const int c = ((kk * 4 + fs) ^ csA) * 8;      // swizzled fragment column
      short8 af[4];
#pragma unroll
      for (int mi = 0; mi < 4; ++mi)
        af[mi] = *reinterpret_cast<const short8*>(&lA[(wm * 64 + mi * 16 + fr) * BK + c]);
#pragma unroll
      for (int ni = 0; ni < 4; ++ni) {
        short8 b1f = *reinterpret_cast<const short8*>(&lB1[(wn * 64 + ni * 16 + fr) * BK + c]);
        short8 b3f = *reinterpret_cast<const short8*>(&lB3[(wn * 64 + ni * 16 + fr) * BK + c]);
#pragma unroll
        for (int mi = 0; mi < 4; ++mi) {
          acc1[mi][ni] = __builtin_amdgcn_mfma_f32_16x16x32_bf16(af[mi], b1f, acc1[mi][ni], 0, 0, 0);
          acc3[mi][ni] = __builtin_amdgcn_mfma_f32_16x16x32_bf16(af[mi], b3f, acc3[mi][ni], 0, 0, 0);
        }
      }
    }
    __syncthreads();
  }

  const float* bp1 = bias1 + (size_t)e * N;
  const float* bp3 = bias3 + (size_t)e * N;
#pragma unroll
  for (int mi = 0; mi < 4; ++mi) {
#pragma unroll
    for (int j = 0; j < 4; ++j) {
      int p = mt * BM + wm * 64 + mi * 16 + fs * 4 + j;   // C/D: row=(lane>>4)*4+j
      if (p >= M) continue;
      size_t hrow = GATHER ? (size_t)bkt[p] : (size_t)p;
      u16* hp = H + hrow * N;
#pragma unroll
      for (int ni = 0; ni < 4; ++ni) {
        int gcol = nt * BN + wn * 64 + ni * 16 + fr;      // C/D: col=lane&15
        float v1 = acc1[mi][ni][j] + bp1[gcol];
        float v3 = acc3[mi][ni][j] + bp3[gcol];
        float hv = (v1 / (1.0f + __expf(-v1))) * v3;
        hp[gcol] = f2bf(hv);
      }
    }
  }
}

// ---------------- GEMM2: out = (A@B^T + bias) [*w, scatter-atomic | plain store] ----------------
template <bool GATHER>
__global__ void __launch_bounds__(256, 2) k_gemm2(
    const u16* __restrict__ A, const u16* __restrict__ B,
    const float* __restrict__ bias, const float* __restrict__ tokw,
    float* __restrict__ OUT, const int* __restrict__ counts, const int* __restrict__ bucket,
    int N, int K) {
  const int e = blockIdx.z;
  const int M = GATHER ? counts[e] : T_TOK;
  const int mt = blockIdx.y;
  if (mt * BM >= M) return;
  const int nt = blockIdx.x;
  const int tid = threadIdx.x;
  const int lane = tid & 63;
  const int wid = tid >> 6;

  __shared__ __align__(16) u16 lA[BM * BK];
  __shared__ __align__(16) u16 lB[BM * BK];

  const int srow = tid >> 3;
  const int sc16 = tid & 7;
  const int scsw = (sc16 ^ (srow & 7)) * 8;
  const int* bkt = bucket + e * CAP;

  const u16* aptr[4]; const u16* bptr[4];
#pragma unroll
  for (int p = 0; p < 4; ++p) {
    int r = mt * BM + srow + p * 32;
    size_t arow;
    if (GATHER) { int pos = r < M ? r : M - 1; arow = (size_t)bkt[pos]; }
    else arow = (size_t)r;
    aptr[p] = A + arow * K + scsw;
    size_t nrow = (size_t)e * N + nt * BN + srow + p * 32;
    bptr[p] = B + nrow * K + scsw;
  }

  f32x4 acc[4][4];
#pragma unroll
  for (int i = 0; i < 4; ++i)
#pragma unroll
    for (int j = 0; j < 4; ++j) acc[i][j] = f32x4{0.f, 0.f, 0.f, 0.f};

  const int wm = wid >> 1, wn = wid & 1;
  const int fr = lane & 15, fs = lane >> 4;
  const int csA = fr & 7;

  for (int kt = 0; kt < K; kt += BK) {
#pragma unroll
    for (int p = 0; p < 4; ++p) {
      int ldso = (srow + 32 * p) * BK + sc16 * 8;
      gload16(aptr[p] + kt, &lA[ldso]);
      gload16(bptr[p] + kt, &lB[ldso]);
    }
    __syncthreads();
#pragma unroll
    for (int kk = 0; kk < 2; ++kk) {
      const int c = ((kk * 4 + fs) ^ csA) * 8;
      short8 af[4];
#pragma unroll
      for (int mi = 0; mi < 4; ++mi)
        af[mi] = *reinterpret_cast<const short8*>(&lA[(wm * 64 + mi * 16 + fr) * BK + c]);
#pragma unroll
      for (int ni = 0; ni < 4; ++ni) {
        short8 bf = *reinterpret_cast<const short8*>(&lB[(wn * 64 + ni * 16 + fr) * BK + c]);
#pragma unroll
        for (int mi = 0; mi < 4; ++mi)
          acc[mi][ni] = __builtin_amdgcn_mfma_f32_16x16x32_bf16(af[mi], bf, acc[mi][ni], 0, 0, 0);
      }
    }
    __syncthreads();
  }

#pragma unroll
  for (int mi = 0; mi < 4; ++mi) {
#pragma unroll
    for (int j = 0; j < 4; ++j) {
      int p = mt * BM + wm * 64 + mi * 16 + fs * 4 + j;
      if (p >= M) continue;
#pragma unroll
      for (int ni = 0; ni < 4; ++ni) {
        int gcol = nt * BN + wn * 64 + ni * 16 + fr;
        float v = acc[mi][ni][j] + bias[(size_t)e * N + gcol];
        if (GATHER) {
          int slot = bkt[p];
          float w = tokw[slot];
          atomicAdd(&OUT[(size_t)(slot >> 1) * DIM + gcol], v * w);
        } else {
          OUT[(size_t)p * DIM + gcol] = v;
        }
      }
    }
  }
}

extern "C" void kernel_launch(void* const* d_in, const int* in_sizes, int n_in,
                              void* d_out, int out_size, void* d_ws, size_t ws_size,
                              hipStream_t stream) {
  const float* x   = (const float*)d_in[0];
  const float* gw  = (const float*)d_in[1];
  const float* gb  = (const float*)d_in[2];
  const float* We1 = (const float*)d_in[3];
  const float* be1 = (const float*)d_in[4];
  const float* We2 = (const float*)d_in[5];
  const float* be2 = (const float*)d_in[6];
  const float* We3 = (const float*)d_in[7];
  const float* be3 = (const float*)d_in[8];
  const float* ws1 = (const float*)d_in[9];
  const float* bs1 = (const float*)d_in[10];
  const float* ws2 = (const float*)d_in[11];
  const float* bs2 = (const float*)d_in[12];
  const float* ws3 = (const float*)d_in[13];
  const float* bs3 = (const float*)d_in[14];
  float* out = (float*)d_out;

  // workspace carve (all regions 256B aligned); total ~71 MB
  char* w = (char*)d_ws;
  int*   counts = (int*)w;   w += 256;
  int*   bucket = (int*)w;   w += (size_t)NEXP * CAP * 4;
  float* tokw   = (float*)w; w += (size_t)2 * T_TOK * 4;
  double* scor  = (double*)w; w += (size_t)T_TOK * NEXP * 8;
  u16*   xb     = (u16*)w;   w += (size_t)T_TOK * DIM * 2;
  u16*   w1t    = (u16*)w;   w += (size_t)NEXP * INTER * DIM * 2;
  u16*   w3t    = (u16*)w;   w += (size_t)NEXP * INTER * DIM * 2;
  u16*   w2t    = (u16*)w;   w += (size_t)NEXP * DIM * INTER * 2;
  u16*   s1t    = (u16*)w;   w += (size_t)NSH * DIM * 2;
  u16*   s3t    = (u16*)w;   w += (size_t)NSH * DIM * 2;
  u16*   s2t    = (u16*)w;   w += (size_t)DIM * NSH * 2;
  u16*   hbuf   = (u16*)w;   w += (size_t)2 * T_TOK * INTER * 2;  // aliased: hs [T][NSH] then h [2T][INTER]

  hipMemsetAsync(counts, 0, 64, stream);
  k_cvt<<<(T_TOK * DIM) / (256 * 4), 256, 0, stream>>>(x, xb, T_TOK * DIM);
  dim3 tb(32, 8);
  k_tr<<<dim3(INTER / 32, DIM / 32, NEXP), tb, 0, stream>>>(We1, w1t, DIM, INTER);
  k_tr<<<dim3(INTER / 32, DIM / 32, NEXP), tb, 0, stream>>>(We3, w3t, DIM, INTER);
  k_tr<<<dim3(DIM / 32, INTER / 32, NEXP), tb, 0, stream>>>(We2, w2t, INTER, DIM);
  k_tr<<<dim3(NSH / 32, DIM / 32, 1), tb, 0, stream>>>(ws1, s1t, DIM, NSH);
  k_tr<<<dim3(NSH / 32, DIM / 32, 1), tb, 0, stream>>>(ws3, s3t, DIM, NSH);
  k_tr<<<dim3(DIM / 32, NSH / 32, 1), tb, 0, stream>>>(ws2, s2t, NSH, DIM);
  k_score<<<T_TOK / 16, 512, 0, stream>>>(x, gw, scor);
  k_route<<<T_TOK / 256, 256, 0, stream>>>(scor, gb, counts, bucket, tokw);

  // shared expert path: writes z to every d_out element (plain stores)
  k_gemm1<false><<<dim3(NSH / BN, T_TOK / BM, 1), 256, 0, stream>>>(
      xb, s1t, s3t, bs1, bs3, hbuf, counts, bucket, NSH, DIM);
  k_gemm2<false><<<dim3(DIM / BN, T_TOK / BM, 1), 256, 0, stream>>>(
      hbuf, s2t, bs2, tokw, out, counts, bucket, DIM, NSH);
  // routed expert path: atomicAdd on top of z
  k_gemm1<true><<<dim3(INTER / BN, CAP / BM, NEXP), 256, 0, stream>>>(
      xb, w1t, w3t, be1, be3, hbuf, counts, bucket, INTER, DIM);
  k_gemm2<true><<<dim3(DIM / BN, CAP / BM, NEXP), 256, 0, stream>>>(
      hbuf, w2t, be2, tokw, out, counts, bucket, DIM, INTER);
}

// Round 3
// 225.890 us; speedup vs baseline: 1.3542x; 1.1321x over previous
//
#include <hip/hip_runtime.h>

typedef unsigned short u16;
typedef unsigned int u32;
typedef __attribute__((ext_vector_type(8))) short short8;
typedef __attribute__((ext_vector_type(4))) float f32x4;

#define T_TOK 4096
#define DIM   1024
#define NEXP  16
#define INTER 512
#define NSH   1024
#define CAP   4096
#define BM 128
#define BN 128
#define BK 64

__device__ __forceinline__ u16 f2bf(float f) {
  union { float f; u32 u; } c; c.f = f;
  u32 u = c.u;
  return (u16)((u + 0x7FFFu + ((u >> 16) & 1u)) >> 16);
}

typedef __attribute__((address_space(1))) u32 u32_g;
typedef __attribute__((address_space(3))) u32 u32_l;
__device__ __forceinline__ void gload16(const u16* g, u16* l) {
  __builtin_amdgcn_global_load_lds((u32_g*)g, (u32_l*)l, 16, 0, 0);
}

// ---------------- gate phase A: fp64 scores = x @ gw^T ----------------
__global__ void __launch_bounds__(512) k_score(const float* __restrict__ x,
                                               const float* __restrict__ gw,
                                               double* __restrict__ scores) {
  const int tid = threadIdx.x;
  const int h  = tid >> 8;
  const int tk = (tid >> 4) & 15;
  const int e  = tid & 15;
  const int t  = blockIdx.x * 16 + tk;
  const float* xr = x + (size_t)t * DIM + h * 512;
  const float* wr = gw + (size_t)e * DIM + h * 512;
  double p = 0.0;
#pragma unroll 8
  for (int i = 0; i < 128; ++i) {
    float4 xv = *reinterpret_cast<const float4*>(xr + i * 4);
    float4 wv = *reinterpret_cast<const float4*>(wr + i * 4);
    p += (double)xv.x * (double)wv.x;
    p += (double)xv.y * (double)wv.y;
    p += (double)xv.z * (double)wv.z;
    p += (double)xv.w * (double)wv.w;
  }
  __shared__ double part[512];
  part[tid] = p;
  __syncthreads();
  if (tid < 256) scores[(size_t)t * NEXP + e] = part[tid] + part[tid + 256];
}

// ---------------- gate phase B: softmax + group-limited top-2, one thread/token ----------------
__global__ void __launch_bounds__(256) k_route(const double* __restrict__ scores,
                                               const float* __restrict__ gb,
                                               int* __restrict__ counts,
                                               int* __restrict__ bucket,
                                               float* __restrict__ tokw) {
  const int t = blockIdx.x * 256 + threadIdx.x;
  double s[NEXP];
#pragma unroll
  for (int e = 0; e < NEXP; ++e) s[e] = scores[(size_t)t * NEXP + e];
  double m = s[0];
#pragma unroll
  for (int e = 1; e < NEXP; ++e) m = s[e] > m ? s[e] : m;
  double ex[NEXP], sum = 0.0;
#pragma unroll
  for (int e = 0; e < NEXP; ++e) { ex[e] = exp(s[e] - m); sum += ex[e]; }
  double orig[NEXP], sc[NEXP];
#pragma unroll
  for (int e = 0; e < NEXP; ++e) { orig[e] = ex[e] / sum; sc[e] = orig[e] + (double)gb[e]; }
  double gs[4];
#pragma unroll
  for (int g = 0; g < 4; ++g) {
    double m1 = -1e300, m2 = -1e300;
#pragma unroll
    for (int j = 0; j < 4; ++j) {
      double v = sc[g * 4 + j];
      if (v > m1) { m2 = m1; m1 = v; } else if (v > m2) m2 = v;
    }
    gs[g] = m1 + m2;
  }
  int g1 = 0;
  for (int g = 1; g < 4; ++g) if (gs[g] > gs[g1]) g1 = g;
  int g2 = -1;
  for (int g = 0; g < 4; ++g) { if (g == g1) continue; if (g2 < 0 || gs[g] > gs[g2]) g2 = g; }
  int e1 = -1, e2 = -1;
  for (int e = 0; e < NEXP; ++e) {
    int g = e >> 2;
    if (g != g1 && g != g2) continue;
    if (e1 < 0 || sc[e] > sc[e1]) e1 = e;
  }
  for (int e = 0; e < NEXP; ++e) {
    int g = e >> 2;
    if ((g != g1 && g != g2) || e == e1) continue;
    if (e2 < 0 || sc[e] > sc[e2]) e2 = e;
  }
  tokw[2 * t]     = (float)orig[e1];
  tokw[2 * t + 1] = (float)orig[e2];
  int p0 = atomicAdd(&counts[e1], 1); bucket[e1 * CAP + p0] = 2 * t;
  int p1 = atomicAdd(&counts[e2], 1); bucket[e2 * CAP + p1] = 2 * t + 1;
}

// ---------------- fp32 -> bf16 convert (vectorized) ----------------
__global__ void k_cvt(const float* __restrict__ src, u16* __restrict__ dst, int n) {
  int i = (blockIdx.x * blockDim.x + threadIdx.x) * 4;
  if (i >= n) return;
  float4 v = *reinterpret_cast<const float4*>(src + i);
  ushort4 o;
  o.x = f2bf(v.x); o.y = f2bf(v.y); o.z = f2bf(v.z); o.w = f2bf(v.w);
  *reinterpret_cast<ushort4*>(dst + i) = o;
}

// ---------------- fused transpose-convert, 1-D decoded over 6 jobs ----------------
struct TrJob { const float* src; u16* dst; int R, C, base; };
struct TrJobs { TrJob j[6]; };

__global__ void k_tr_all(TrJobs J) {
  const int id = blockIdx.x;
  int k = 0;
#pragma unroll
  for (int q = 1; q < 6; ++q) if (id >= J.j[q].base) k = q;
  const TrJob jb = J.j[k];
  const int rx = jb.C >> 5, ry = jb.R >> 5;
  const int per = rx * ry;
  int rel = id - jb.base;
  const int b = rel / per; rel -= b * per;
  const int r0 = (rel / rx) << 5;
  const int c0 = (rel - (rel / rx) * rx) << 5;
  const float* src = jb.src + (size_t)b * jb.R * jb.C;
  u16* dst = jb.dst + (size_t)b * jb.R * jb.C;

  __shared__ float tile[32][33];
  const int tx = threadIdx.x, ty = threadIdx.y;
#pragma unroll
  for (int i = 0; i < 4; ++i)
    tile[ty + 8 * i][tx] = src[(size_t)(r0 + ty + 8 * i) * jb.C + c0 + tx];
  __syncthreads();
#pragma unroll
  for (int i = 0; i < 4; ++i)
    dst[(size_t)(c0 + ty + 8 * i) * jb.R + r0 + tx] = f2bf(tile[tx][ty + 8 * i]);
}

// ---------------- fused GEMM1 (routed z<16 | shared z==16): h = silu(.)*(.)  ----------------
__global__ void __launch_bounds__(256, 2) k_g1(
    const u16* __restrict__ A, const u16* __restrict__ w1t, const u16* __restrict__ w3t,
    const u16* __restrict__ s1t, const u16* __restrict__ s3t,
    const float* __restrict__ be1, const float* __restrict__ be3,
    const float* __restrict__ bs1, const float* __restrict__ bs3,
    u16* __restrict__ hr, u16* __restrict__ hs,
    const int* __restrict__ counts, const int* __restrict__ bucket) {
  const int z = blockIdx.z;
  const bool sh = (z == NEXP);
  const int N = sh ? NSH : INTER;
  const int nt = blockIdx.x;
  if (nt * BN >= N) return;
  const int M = sh ? T_TOK : counts[z];
  const int mt = blockIdx.y;
  if (mt * BM >= M) return;
  const int tid = threadIdx.x;
  const int lane = tid & 63, wid = tid >> 6;

  __shared__ __align__(16) u16 lA[BM * BK];
  __shared__ __align__(16) u16 lB1[BM * BK];
  __shared__ __align__(16) u16 lB3[BM * BK];

  const int srow = tid >> 3, sc16 = tid & 7;
  const int scsw = (sc16 ^ (srow & 7)) * 8;
  const int* bkt = bucket + z * CAP;
  const u16* B1 = sh ? s1t : w1t + (size_t)z * INTER * DIM;
  const u16* B3 = sh ? s3t : w3t + (size_t)z * INTER * DIM;

  const u16 *aptr[4], *b1ptr[4], *b3ptr[4];
#pragma unroll
  for (int p = 0; p < 4; ++p) {
    int r = mt * BM + srow + p * 32;
    size_t arow;
    if (sh) arow = (size_t)r;
    else { int pos = r < M ? r : M - 1; arow = (size_t)(bkt[pos] >> 1); }
    aptr[p] = A + arow * DIM + scsw;
    size_t nrow = (size_t)(nt * BN + srow + p * 32);
    b1ptr[p] = B1 + nrow * DIM + scsw;
    b3ptr[p] = B3 + nrow * DIM + scsw;
  }

  f32x4 acc1[4][4], acc3[4][4];
#pragma unroll
  for (int i = 0; i < 4; ++i)
#pragma unroll
    for (int j = 0; j < 4; ++j) {
      acc1[i][j] = f32x4{0.f, 0.f, 0.f, 0.f};
      acc3[i][j] = f32x4{0.f, 0.f, 0.f, 0.f};
    }

  const int wm = wid >> 1, wn = wid & 1;
  const int fr = lane & 15, fs = lane >> 4;
  const int csA = fr & 7;

  for (int kt = 0; kt < DIM; kt += BK) {
#pragma unroll
    for (int p = 0; p < 4; ++p) {
      int ldso = (srow + 32 * p) * BK + sc16 * 8;
      gload16(aptr[p] + kt, &lA[ldso]);
      gload16(b1ptr[p] + kt, &lB1[ldso]);
      gload16(b3ptr[p] + kt, &lB3[ldso]);
    }
    __syncthreads();
#pragma unroll
    for (int kk = 0; kk < 2; ++kk) {
      const int c = ((kk * 4 + fs) ^ csA) * 8;
      short8 af[4];
#pragma unroll
      for (int mi = 0; mi < 4; ++mi)
        af[mi] = *reinterpret_cast<const short8*>(&lA[(wm * 64 + mi * 16 + fr) * BK + c]);
#pragma unroll
      for (int ni = 0; ni < 4; ++ni) {
        short8 b1f = *reinterpret_cast<const short8*>(&lB1[(wn * 64 + ni * 16 + fr) * BK + c]);
        short8 b3f = *reinterpret_cast<const short8*>(&lB3[(wn * 64 + ni * 16 + fr) * BK + c]);
#pragma unroll
        for (int mi = 0; mi < 4; ++mi) {
          acc1[mi][ni] = __builtin_amdgcn_mfma_f32_16x16x32_bf16(af[mi], b1f, acc1[mi][ni], 0, 0, 0);
          acc3[mi][ni] = __builtin_amdgcn_mfma_f32_16x16x32_bf16(af[mi], b3f, acc3[mi][ni], 0, 0, 0);
        }
      }
    }
    __syncthreads();
  }

  const float* bp1 = sh ? bs1 : be1 + (size_t)z * INTER;
  const float* bp3 = sh ? bs3 : be3 + (size_t)z * INTER;
#pragma unroll
  for (int mi = 0; mi < 4; ++mi) {
#pragma unroll
    for (int j = 0; j < 4; ++j) {
      int p = mt * BM + wm * 64 + mi * 16 + fs * 4 + j;
      if (p >= M) continue;
      u16* hp = sh ? hs + (size_t)p * NSH : hr + (size_t)bkt[p] * INTER;
#pragma unroll
      for (int ni = 0; ni < 4; ++ni) {
        int gcol = nt * BN + wn * 64 + ni * 16 + fr;
        float v1 = acc1[mi][ni][j] + bp1[gcol];
        float v3 = acc3[mi][ni][j] + bp3[gcol];
        float hv = (v1 / (1.0f + __expf(-v1))) * v3;
        hp[gcol] = f2bf(hv);
      }
    }
  }
}

// ---------------- fused GEMM2 (routed -> ybuf | shared -> out), plain stores ----------------
__global__ void __launch_bounds__(256, 2) k_g2(
    const u16* __restrict__ hr, const u16* __restrict__ hs,
    const u16* __restrict__ w2t, const u16* __restrict__ s2t,
    const float* __restrict__ be2, const float* __restrict__ bs2,
    float* __restrict__ yb, float* __restrict__ out,
    const int* __restrict__ counts, const int* __restrict__ bucket) {
  const int z = blockIdx.z;
  const bool sh = (z == NEXP);
  const int K = sh ? NSH : INTER;
  const int M = sh ? T_TOK : counts[z];
  const int mt = blockIdx.y;
  if (mt * BM >= M) return;
  const int nt = blockIdx.x;
  const int tid = threadIdx.x;
  const int lane = tid & 63, wid = tid >> 6;

  __shared__ __align__(16) u16 lA[BM * BK];
  __shared__ __align__(16) u16 lB[BM * BK];

  const int srow = tid >> 3, sc16 = tid & 7;
  const int scsw = (sc16 ^ (srow & 7)) * 8;
  const int* bkt = bucket + z * CAP;
  const u16* Ab = sh ? hs : hr;
  const u16* Bb = sh ? s2t : w2t + (size_t)z * DIM * INTER;

  const u16 *aptr[4], *bptr[4];
#pragma unroll
  for (int p = 0; p < 4; ++p) {
    int r = mt * BM + srow + p * 32;
    size_t arow;
    if (sh) arow = (size_t)r;
    else { int pos = r < M ? r : M - 1; arow = (size_t)bkt[pos]; }
    aptr[p] = Ab + arow * K + scsw;
    size_t nrow = (size_t)(nt * BN + srow + p * 32);
    bptr[p] = Bb + nrow * K + scsw;
  }

  f32x4 acc[4][4];
#pragma unroll
  for (int i = 0; i < 4; ++i)
#pragma unroll
    for (int j = 0; j < 4; ++j) acc[i][j] = f32x4{0.f, 0.f, 0.f, 0.f};

  const int wm = wid >> 1, wn = wid & 1;
  const int fr = lane & 15, fs = lane >> 4;
  const int csA = fr & 7;

  for (int kt = 0; kt < K; kt += BK) {
#pragma unroll
    for (int p = 0; p < 4; ++p) {
      int ldso = (srow + 32 * p) * BK + sc16 * 8;
      gload16(aptr[p] + kt, &lA[ldso]);
      gload16(bptr[p] + kt, &lB[ldso]);
    }
    __syncthreads();
#pragma unroll
    for (int kk = 0; kk < 2; ++kk) {
      const int c = ((kk * 4 + fs) ^ csA) * 8;
      short8 af[4];
#pragma unroll
      for (int mi = 0; mi < 4; ++mi)
        af[mi] = *reinterpret_cast<const short8*>(&lA[(wm * 64 + mi * 16 + fr) * BK + c]);
#pragma unroll
      for (int ni = 0; ni < 4; ++ni) {
        short8 bf = *reinterpret_cast<const short8*>(&lB[(wn * 64 + ni * 16 + fr) * BK + c]);
#pragma unroll
        for (int mi = 0; mi < 4; ++mi)
          acc[mi][ni] = __builtin_amdgcn_mfma_f32_16x16x32_bf16(af[mi], bf, acc[mi][ni], 0, 0, 0);
      }
    }
    __syncthreads();
  }

  const float* bp = sh ? bs2 : be2 + (size_t)z * DIM;
#pragma unroll
  for (int mi = 0; mi < 4; ++mi) {
#pragma unroll
    for (int j = 0; j < 4; ++j) {
      int p = mt * BM + wm * 64 + mi * 16 + fs * 4 + j;
      if (p >= M) continue;
      float* orow = sh ? out + (size_t)p * DIM : yb + (size_t)bkt[p] * DIM;
#pragma unroll
      for (int ni = 0; ni < 4; ++ni) {
        int gcol = nt * BN + wn * 64 + ni * 16 + fr;
        orow[gcol] = acc[mi][ni][j] + bp[gcol];
      }
    }
  }
}

// ---------------- final combine: out += w0*y[2t] + w1*y[2t+1] ----------------
__global__ void __launch_bounds__(256) k_comb(float* __restrict__ out,
                                              const float* __restrict__ yb,
                                              const float* __restrict__ tokw) {
  const int i = blockIdx.x * 256 + threadIdx.x;   // float4 index over [T][256]
  const int t = i >> 8, c4 = i & 255;
  const float w0 = tokw[2 * t], w1 = tokw[2 * t + 1];
  const float4* y0 = (const float4*)yb + ((size_t)(2 * t) << 8);
  const float4* y1 = y0 + 256;
  float4* o = (float4*)out + ((size_t)t << 8);
  float4 a = o[c4];
  float4 p = y0[c4], q = y1[c4];
  a.x += w0 * p.x + w1 * q.x;
  a.y += w0 * p.y + w1 * q.y;
  a.z += w0 * p.z + w1 * q.z;
  a.w += w0 * p.w + w1 * q.w;
  o[c4] = a;
}

extern "C" void kernel_launch(void* const* d_in, const int* in_sizes, int n_in,
                              void* d_out, int out_size, void* d_ws, size_t ws_size,
                              hipStream_t stream) {
  const float* x   = (const float*)d_in[0];
  const float* gw  = (const float*)d_in[1];
  const float* gb  = (const float*)d_in[2];
  const float* We1 = (const float*)d_in[3];
  const float* be1 = (const float*)d_in[4];
  const float* We2 = (const float*)d_in[5];
  const float* be2 = (const float*)d_in[6];
  const float* We3 = (const float*)d_in[7];
  const float* be3 = (const float*)d_in[8];
  const float* ws1 = (const float*)d_in[9];
  const float* bs1 = (const float*)d_in[10];
  const float* ws2 = (const float*)d_in[11];
  const float* bs2 = (const float*)d_in[12];
  const float* ws3 = (const float*)d_in[13];
  const float* bs3 = (const float*)d_in[14];
  float* out = (float*)d_out;

  // workspace carve (~83 MB). ybuf (33.6 MB fp32) aliases xb+w1t+w3t (41.9 MB),
  // all dead by the time k_g2 writes it.
  char* w = (char*)d_ws;
  int*    counts = (int*)w;    w += 256;
  int*    bucket = (int*)w;    w += (size_t)NEXP * CAP * 4;
  float*  tokw   = (float*)w;  w += (size_t)2 * T_TOK * 4;
  double* scor   = (double*)w; w += (size_t)T_TOK * NEXP * 8;
  char*   alias0 = w;
  u16*    xb     = (u16*)w;    w += (size_t)T_TOK * DIM * 2;
  u16*    w1t    = (u16*)w;    w += (size_t)NEXP * INTER * DIM * 2;
  u16*    w3t    = (u16*)w;    w += (size_t)NEXP * INTER * DIM * 2;
  u16*    w2t    = (u16*)w;    w += (size_t)NEXP * DIM * INTER * 2;
  u16*    s1t    = (u16*)w;    w += (size_t)NSH * DIM * 2;
  u16*    s3t    = (u16*)w;    w += (size_t)NSH * DIM * 2;
  u16*    s2t    = (u16*)w;    w += (size_t)DIM * NSH * 2;
  u16*    hr     = (u16*)w;    w += (size_t)2 * T_TOK * INTER * 2;
  u16*    hs     = (u16*)w;    w += (size_t)T_TOK * NSH * 2;
  float*  ybuf   = (float*)alias0;

  hipMemsetAsync(counts, 0, 64, stream);
  k_cvt<<<(T_TOK * DIM) / (256 * 4), 256, 0, stream>>>(x, xb, T_TOK * DIM);

  // fused transposes: per-job tile counts -> cumulative bases
  TrJobs J;
  int base = 0;
  auto addJob = [&](int idx, const float* s, u16* d, int R, int C, int nb) {
    J.j[idx] = TrJob{s, d, R, C, base};
    base += nb * (R / 32) * (C / 32);
  };
  addJob(0, We1, w1t, DIM, INTER, NEXP);
  addJob(1, We3, w3t, DIM, INTER, NEXP);
  addJob(2, We2, w2t, INTER, DIM, NEXP);
  addJob(3, ws1, s1t, DIM, NSH, 1);
  addJob(4, ws3, s3t, DIM, NSH, 1);
  addJob(5, ws2, s2t, NSH, DIM, 1);
  k_tr_all<<<base, dim3(32, 8), 0, stream>>>(J);

  k_score<<<T_TOK / 16, 512, 0, stream>>>(x, gw, scor);
  k_route<<<T_TOK / 256, 256, 0, stream>>>(scor, gb, counts, bucket, tokw);

  // phase A: all first-layer SwiGLU GEMMs (routed experts z=0..15, shared z=16)
  k_g1<<<dim3(NSH / BN, 32, NEXP + 1), 256, 0, stream>>>(
      xb, w1t, w3t, s1t, s3t, be1, be3, bs1, bs3, hr, hs, counts, bucket);
  // phase B: all second-layer GEMMs; shared -> out, routed -> ybuf (disjoint, no atomics)
  k_g2<<<dim3(DIM / BN, 32, NEXP + 1), 256, 0, stream>>>(
      hr, hs, w2t, s2t, be2, bs2, ybuf, out, counts, bucket);
  // final: out += w0*y[e1] + w1*y[e2]
  k_comb<<<(T_TOK * DIM / 4) / 256, 256, 0, stream>>>(out, ybuf, tokw);
}